// Round 2
// baseline (293.661 us; speedup 1.0000x reference)
//
#include <hip/hip_runtime.h>

#define VOCAB 9892
#define EMB   100
#define HID   10
#define BATCH 256
#define TLEN  2048

template <int N>
static __device__ __forceinline__ float dpp_ror(float v) {
    int i = __builtin_bit_cast(int, v);
    i = __builtin_amdgcn_mov_dpp(i, 0x120 + N, 0xF, 0xF, true); // row_ror:N
    return __builtin_bit_cast(float, i);
}

// ---------------------------------------------------------------------------
// Kernel 1: P[v][0..15] = sum_e emb[v,e]*W_ih[l,e] + b_ih[l] + b_hh[l] (pad 0)
//           Wd[k][l]    = W_hh[l][sigma_k(l)]  (diagonal layout, built with the
//           SAME DPP rotation the scan uses -> direction-proof)
// ---------------------------------------------------------------------------
__global__ __launch_bounds__(64) void prep_kernel(
    const float* __restrict__ emb,
    const float* __restrict__ W_ih,
    const float* __restrict__ W_hh,
    const float* __restrict__ b_ih,
    const float* __restrict__ b_hh,
    float* __restrict__ P, float* __restrict__ Wd)
{
    __shared__ float sW[HID * EMB];
    __shared__ float sB[HID];
    const int tid = threadIdx.x;

    for (int i = tid; i < HID * EMB; i += 64) sW[i] = W_ih[i];
    if (tid < HID) sB[tid] = b_ih[tid] + b_hh[tid];
    __syncthreads();

    // Build Wd in block 0 (all 64 lanes execute the DPP; lanes<16 store)
    if (blockIdx.x == 0) {
        int idx = tid & 15;  // lane's current rotated source index
        #pragma unroll
        for (int k = 0; k < 16; ++k) {
            if (tid < 16) {
                float wv = 0.0f;
                if (tid < HID && idx < HID)
                    wv = W_hh[tid * HID + idx];
                Wd[k * 16 + tid] = wv;
            }
            idx = __builtin_amdgcn_mov_dpp(idx, 0x121, 0xF, 0xF, true); // row_ror:1
        }
    }

    const int v = blockIdx.x * 64 + tid;
    if (v < VOCAB) {
        float acc[HID];
        #pragma unroll
        for (int l = 0; l < HID; ++l) acc[l] = sB[l];
        // emb row: 100 fp32 = 400 B, 16B-aligned -> 25 x float4
        const float4* erow = (const float4*)(emb + (size_t)v * EMB);
        #pragma unroll 5
        for (int q = 0; q < EMB / 4; ++q) {
            float4 e4 = erow[q];
            const int e = 4 * q;
            #pragma unroll
            for (int l = 0; l < HID; ++l) {
                float a = acc[l];
                a = fmaf(e4.x, sW[l * EMB + e + 0], a);
                a = fmaf(e4.y, sW[l * EMB + e + 1], a);
                a = fmaf(e4.z, sW[l * EMB + e + 2], a);
                a = fmaf(e4.w, sW[l * EMB + e + 3], a);
                acc[l] = a;
            }
        }
        float4* Pr = (float4*)(P + (size_t)v * 16);
        Pr[0] = make_float4(acc[0], acc[1], acc[2], acc[3]);
        Pr[1] = make_float4(acc[4], acc[5], acc[6], acc[7]);
        Pr[2] = make_float4(acc[8], acc[9], 0.f, 0.f);
        Pr[3] = make_float4(0.f, 0.f, 0.f, 0.f);
    }
}

// ---------------------------------------------------------------------------
// Kernel 2: the sequential scan. 16 lanes per batch element, 4 per wave,
// 64 blocks x 64 threads. h_l lives one-per-lane; matvec via DPP ror ring
// (two parallel 8-hop chains); tanh = 1 - 2/(1+e^{2a}) via v_exp/v_rcp.
// pa gathered from P with 4-8 step software prefetch.
// ---------------------------------------------------------------------------
static __device__ __forceinline__ float rnn_step(float h, float pa, const float w[16]) {
    float r0 = h;
    float r8 = dpp_ror<8>(h);
    float a0 = fmaf(w[0], r0, pa);
    float a1 = w[8] * r8;
    #pragma unroll
    for (int m = 1; m < 8; ++m) {
        r0 = dpp_ror<1>(r0);
        r8 = dpp_ror<1>(r8);
        a0 = fmaf(w[m], r0, a0);
        a1 = fmaf(w[8 + m], r8, a1);
    }
    const float a = a0 + a1;
    const float e = __builtin_amdgcn_exp2f(a * 2.8853900817779268f); // e^(2a)
    const float r = __builtin_amdgcn_rcpf(1.0f + e);
    return fmaf(-2.0f, r, 1.0f);
}

__global__ __launch_bounds__(64) void scan_kernel(
    const int* __restrict__ x,
    const float* __restrict__ P,
    const float* __restrict__ Wd,
    float* __restrict__ hfin)
{
    const int tid = threadIdx.x;
    const int sub = tid & 15;
    const int b = blockIdx.x * 4 + (tid >> 4);
    const int* xb = x + (size_t)b * TLEN;

    float w[16];
    #pragma unroll
    for (int k = 0; k < 16; ++k) w[k] = Wd[k * 16 + sub];

    float h = 0.0f;

    // software pipeline: xv_b = x for steps t+4..t+7; pa_a = P rows for t..t+3
    int   xv_b[4];
    float pa_a[4];
    {
        int xv0[4];
        #pragma unroll
        for (int j = 0; j < 4; ++j) xv0[j] = xb[j];
        #pragma unroll
        for (int j = 0; j < 4; ++j) xv_b[j] = xb[4 + j];
        #pragma unroll
        for (int j = 0; j < 4; ++j) pa_a[j] = P[xv0[j] * 16 + sub];
    }

    for (int t = 0; t < TLEN; t += 4) {
        int   xv_n[4];
        float pa_b[4];
        const int tn = t + 8;
        #pragma unroll
        for (int j = 0; j < 4; ++j) {
            int ti = tn + j;
            if (ti > TLEN - 1) ti = TLEN - 1;
            xv_n[j] = xb[ti];
        }
        #pragma unroll
        for (int j = 0; j < 4; ++j) pa_b[j] = P[xv_b[j] * 16 + sub];
        #pragma unroll
        for (int j = 0; j < 4; ++j) h = rnn_step(h, pa_a[j], w);
        #pragma unroll
        for (int j = 0; j < 4; ++j) { pa_a[j] = pa_b[j]; xv_b[j] = xv_n[j]; }
    }

    hfin[b * 16 + sub] = h;
}

// ---------------------------------------------------------------------------
// Kernel 3: out[b,v] = sum_l hfin[b,l] * U_W[v,l] + U_b[v]  (fp32 out)
// ---------------------------------------------------------------------------
__global__ __launch_bounds__(256) void head_kernel(
    const float* __restrict__ hfin,
    const float* __restrict__ U_W,
    const float* __restrict__ U_b,
    float* __restrict__ out)
{
    const int v = blockIdx.x * 256 + threadIdx.x;
    const int b = blockIdx.y;
    if (v >= VOCAB) return;

    float hv[HID];
    #pragma unroll
    for (int l = 0; l < HID; ++l) hv[l] = hfin[b * 16 + l];

    // U_W row: 10 fp32 = 40 B, 8B-aligned -> 5 x float2
    const float2* uw = (const float2*)(U_W + (size_t)v * HID);
    float acc = U_b[v];
    #pragma unroll
    for (int p = 0; p < 5; ++p) {
        float2 u = uw[p];
        acc = fmaf(u.x, hv[2 * p], acc);
        acc = fmaf(u.y, hv[2 * p + 1], acc);
    }
    out[(size_t)b * VOCAB + v] = acc;
}

extern "C" void kernel_launch(void* const* d_in, const int* in_sizes, int n_in,
                              void* d_out, int out_size, void* d_ws, size_t ws_size,
                              hipStream_t stream)
{
    const int*   x    = (const int*)d_in[0];
    const float* emb  = (const float*)d_in[1];
    const float* W_ih = (const float*)d_in[2];
    const float* W_hh = (const float*)d_in[3];
    const float* b_ih = (const float*)d_in[4];
    const float* b_hh = (const float*)d_in[5];
    const float* U_W  = (const float*)d_in[6];
    const float* U_b  = (const float*)d_in[7];

    float* P    = (float*)d_ws;           // VOCAB*16 fp32 = 633 KB
    float* Wd   = P + (size_t)VOCAB * 16; // 256 fp32
    float* hfin = Wd + 256;               // BATCH*16 fp32

    prep_kernel<<<(VOCAB + 63) / 64, 64, 0, stream>>>(emb, W_ih, W_hh, b_ih, b_hh, P, Wd);
    scan_kernel<<<64, 64, 0, stream>>>(x, P, Wd, hfin);
    head_kernel<<<dim3((VOCAB + 255) / 256, BATCH), 256, 0, stream>>>(
        hfin, U_W, U_b, (float*)d_out);
}

// Round 3
// 264.592 us; speedup vs baseline: 1.1099x; 1.1099x over previous
//
#include <hip/hip_runtime.h>

#define VOCAB 9892
#define EMB   100
#define HID   10
#define BATCH 256
#define TLEN  2048
#define KSC   2.8853900817779268f  // 2/ln2, folded into P and Wd

template <int N>
static __device__ __forceinline__ float dpp_ror(float v) {
    int i = __builtin_bit_cast(int, v);
    i = __builtin_amdgcn_mov_dpp(i, 0x120 + N, 0xF, 0xF, true); // row_ror:N
    return __builtin_bit_cast(float, i);
}

// ---------------------------------------------------------------------------
// Kernel 1: P[v][l] = KSC*(sum_e emb[v,e]*W_ih[l,e] + b_ih[l] + b_hh[l]), pad 0
//           Wd[k][l] = KSC * W_hh[l][sigma_k(l)]   (diagonal layout built with
//           the SAME DPP rotation the scan uses -> direction-proof)
// ---------------------------------------------------------------------------
__global__ __launch_bounds__(64) void prep_kernel(
    const float* __restrict__ emb,
    const float* __restrict__ W_ih,
    const float* __restrict__ W_hh,
    const float* __restrict__ b_ih,
    const float* __restrict__ b_hh,
    float* __restrict__ P, float* __restrict__ Wd)
{
    __shared__ float sW[HID * EMB];
    __shared__ float sB[HID];
    const int tid = threadIdx.x;

    for (int i = tid; i < HID * EMB; i += 64) sW[i] = W_ih[i];
    if (tid < HID) sB[tid] = b_ih[tid] + b_hh[tid];
    __syncthreads();

    if (blockIdx.x == 0) {
        int idx = tid & 15;  // lane's current rotated source index
        #pragma unroll
        for (int k = 0; k < 16; ++k) {
            if (tid < 16) {
                float wv = 0.0f;
                if (tid < HID && idx < HID)
                    wv = W_hh[tid * HID + idx];
                Wd[k * 16 + tid] = KSC * wv;
            }
            idx = __builtin_amdgcn_mov_dpp(idx, 0x121, 0xF, 0xF, true); // row_ror:1
        }
    }

    const int v = blockIdx.x * 64 + tid;
    if (v < VOCAB) {
        float acc[HID];
        #pragma unroll
        for (int l = 0; l < HID; ++l) acc[l] = sB[l];
        const float4* erow = (const float4*)(emb + (size_t)v * EMB);
        #pragma unroll 5
        for (int q = 0; q < EMB / 4; ++q) {
            float4 e4 = erow[q];
            const int e = 4 * q;
            #pragma unroll
            for (int l = 0; l < HID; ++l) {
                float a = acc[l];
                a = fmaf(e4.x, sW[l * EMB + e + 0], a);
                a = fmaf(e4.y, sW[l * EMB + e + 1], a);
                a = fmaf(e4.z, sW[l * EMB + e + 2], a);
                a = fmaf(e4.w, sW[l * EMB + e + 3], a);
                acc[l] = a;
            }
        }
        float4* Pr = (float4*)(P + (size_t)v * 16);
        Pr[0] = make_float4(KSC * acc[0], KSC * acc[1], KSC * acc[2], KSC * acc[3]);
        Pr[1] = make_float4(KSC * acc[4], KSC * acc[5], KSC * acc[6], KSC * acc[7]);
        Pr[2] = make_float4(KSC * acc[8], KSC * acc[9], 0.f, 0.f);
        Pr[3] = make_float4(0.f, 0.f, 0.f, 0.f);
    }
}

// ---------------------------------------------------------------------------
// Kernel 2: sequential scan. 16 lanes/batch, 4 batches/wave, 64 waves.
// 16-step supersteps, ping-pong register double buffer:
//   superstep i computes on pa_cur; gathers pa_nxt (ss i+1) and x (ss i+2)
//   are issued first -> ~16-step prefetch distance covers HBM miss latency.
// Weights & P pre-scaled by 2/ln2: tanh(a) = 1 - 2*rcp(1 + exp2(a')).
// ---------------------------------------------------------------------------
static __device__ __forceinline__ float rnn_step(float h, float pa, const float w[16]) {
    float r0 = h;
    float r8 = dpp_ror<8>(h);
    float a0 = fmaf(w[0], r0, pa);
    float a1 = w[8] * r8;
    #pragma unroll
    for (int m = 1; m < 8; ++m) {
        r0 = dpp_ror<1>(r0);
        r8 = dpp_ror<1>(r8);
        a0 = fmaf(w[m], r0, a0);
        a1 = fmaf(w[8 + m], r8, a1);
    }
    const float e = __builtin_amdgcn_exp2f(a0 + a1);
    const float r = __builtin_amdgcn_rcpf(1.0f + e);
    return fmaf(-2.0f, r, 1.0f);
}

__global__ __launch_bounds__(64) void scan_kernel(
    const int* __restrict__ x,
    const float* __restrict__ P,
    const float* __restrict__ Wd,
    float* __restrict__ hfin)
{
    const int tid = threadIdx.x;
    const int sub = tid & 15;
    const int b = blockIdx.x * 4 + (tid >> 4);
    const int4* xrow4 = (const int4*)(x + (size_t)b * TLEN);  // 512 int4 per row

    float w[16];
    #pragma unroll
    for (int k = 0; k < 16; ++k) w[k] = Wd[k * 16 + sub];

    float h = 0.0f;

    // ---- prologue: x for ss0 (tmp), x for ss1 (xq0); gather pa0 for ss0 ----
    int4 xq0[4], xq1[4];
    float pa0[16], pa1[16];
    {
        int4 t0[4];
        #pragma unroll
        for (int q = 0; q < 4; ++q) t0[q] = xrow4[q];          // ss0: t=0..15
        #pragma unroll
        for (int q = 0; q < 4; ++q) xq0[q] = xrow4[4 + q];     // ss1: t=16..31
        int vs[16];
        #pragma unroll
        for (int q = 0; q < 4; ++q) {
            vs[4*q+0] = t0[q].x; vs[4*q+1] = t0[q].y;
            vs[4*q+2] = t0[q].z; vs[4*q+3] = t0[q].w;
        }
        #pragma unroll
        for (int j = 0; j < 16; ++j) pa0[j] = P[vs[j] * 16 + sub];
    }

    // BODY: gathers ss(i+1) into NXT using CXQ; x-loads ss(i+2) into NXQ;
    //       computes 16 steps on CUR.
#define SS_BODY(CUR, NXT, CXQ, NXQ, I)                                        \
    {                                                                         \
        int vs[16];                                                           \
        _Pragma("unroll")                                                     \
        for (int q = 0; q < 4; ++q) {                                         \
            vs[4*q+0] = CXQ[q].x; vs[4*q+1] = CXQ[q].y;                       \
            vs[4*q+2] = CXQ[q].z; vs[4*q+3] = CXQ[q].w;                       \
        }                                                                     \
        _Pragma("unroll")                                                     \
        for (int j = 0; j < 16; ++j) NXT[j] = P[vs[j] * 16 + sub];            \
        const int nb = (((I) + 2) & 127) * 4;                                 \
        _Pragma("unroll")                                                     \
        for (int q = 0; q < 4; ++q) NXQ[q] = xrow4[nb + q];                   \
        _Pragma("unroll")                                                     \
        for (int j = 0; j < 16; ++j) h = rnn_step(h, CUR[j], w);              \
    }

    for (int i = 0; i < TLEN / 16; i += 2) {
        SS_BODY(pa0, pa1, xq0, xq1, i)
        SS_BODY(pa1, pa0, xq1, xq0, i + 1)
    }
#undef SS_BODY

    hfin[b * 16 + sub] = h;
}

// ---------------------------------------------------------------------------
// Kernel 3: out[b,v] = sum_l hfin[b,l] * U_W[v,l] + U_b[v]  (fp32 out)
// ---------------------------------------------------------------------------
__global__ __launch_bounds__(256) void head_kernel(
    const float* __restrict__ hfin,
    const float* __restrict__ U_W,
    const float* __restrict__ U_b,
    float* __restrict__ out)
{
    const int v = blockIdx.x * 256 + threadIdx.x;
    const int b = blockIdx.y;
    if (v >= VOCAB) return;

    float hv[HID];
    #pragma unroll
    for (int l = 0; l < HID; ++l) hv[l] = hfin[b * 16 + l];

    const float2* uw = (const float2*)(U_W + (size_t)v * HID);
    float acc = U_b[v];
    #pragma unroll
    for (int p = 0; p < 5; ++p) {
        float2 u = uw[p];
        acc = fmaf(u.x, hv[2 * p], acc);
        acc = fmaf(u.y, hv[2 * p + 1], acc);
    }
    out[(size_t)b * VOCAB + v] = acc;
}

extern "C" void kernel_launch(void* const* d_in, const int* in_sizes, int n_in,
                              void* d_out, int out_size, void* d_ws, size_t ws_size,
                              hipStream_t stream)
{
    const int*   x    = (const int*)d_in[0];
    const float* emb  = (const float*)d_in[1];
    const float* W_ih = (const float*)d_in[2];
    const float* W_hh = (const float*)d_in[3];
    const float* b_ih = (const float*)d_in[4];
    const float* b_hh = (const float*)d_in[5];
    const float* U_W  = (const float*)d_in[6];
    const float* U_b  = (const float*)d_in[7];

    float* P    = (float*)d_ws;           // VOCAB*16 fp32 = 633 KB
    float* Wd   = P + (size_t)VOCAB * 16; // 256 fp32
    float* hfin = Wd + 256;               // BATCH*16 fp32

    prep_kernel<<<(VOCAB + 63) / 64, 64, 0, stream>>>(emb, W_ih, W_hh, b_ih, b_hh, P, Wd);
    scan_kernel<<<64, 64, 0, stream>>>(x, P, Wd, hfin);
    head_kernel<<<dim3((VOCAB + 255) / 256, BATCH), 256, 0, stream>>>(
        hfin, U_W, U_b, (float*)d_out);
}